// Round 1
// baseline (787.545 us; speedup 1.0000x reference)
//
#include <hip/hip_runtime.h>
#include <hip/hip_bf16.h>

// ---------------------------------------------------------------------------
// PlanStructuredNetwork — round 3.
//   R2: 957 us, latency-bound at 2 blocks/CU (register prefetch PF holds
//   64 VGPRs live on top of 72 VGPRs of weights). Changes:
//   * input staging moved from registers to double-buffered LDS via
//     __builtin_amdgcn_global_load_lds (1-2 wave-ops/iter instead of 8
//     per-lane loads); frees ~64 VGPRs -> __launch_bounds__(256,3).
//   * raw s_barrier + counted "s_waitcnt vmcnt(K)" (K = stage ops) so the
//     next tile's loads stay in flight across the barrier (T3/T4); never
//     vmcnt(0) in the loop. __syncthreads would drain vmcnt -> not used.
//   * gload_lds dest must be linear, so the 16B-chunk XOR swizzle
//     (c ^= row&7) is applied to the per-lane GLOBAL source address and
//     to the ds_read addresses (both-sides-or-neither, caveat #21).
//     Feats rows (128 B) and cur child-pairs (128 B) share the pattern;
//     B-frag ds_read_b128s hit 8 accesses/bank = conflict-free minimum.
//   * cur staged viewing cur_in as parent rows of 128 B (children of gr
//     are rows 2gr,2gr+1 = contiguous 128 B) — layout unchanged on disk.
// ws: 114688 B weights + 128 MB curA + 64 MB curB (~192.1 MB).
// ---------------------------------------------------------------------------

typedef _Float16 f16;
typedef _Float16 f16x8 __attribute__((ext_vector_type(8)));
typedef _Float16 f16x4 __attribute__((ext_vector_type(4)));
typedef float    f32x4 __attribute__((ext_vector_type(4)));

#define MFMA16(a, b, c) __builtin_amdgcn_mfma_f32_16x16x32_f16((a), (b), (c), 0, 0, 0)

// ws element offsets (f16) of transposed weights W^T[m][k]
#define OFF_S1 0       // [128][32]
#define OFF_S2 4096    // [128][128]
#define OFF_S3 20480   // [32][128]
#define OFF_J1 24576   // [128][96]
#define OFF_J2 36864   // [128][128]
#define OFF_J3 53248   // [32][128]
#define W_TOTAL 57344
#define CURA_BYTE_OFF 114688   // = W_TOTAL*2

__global__ void prep_weights(const float* __restrict__ sW1,
                             const float* __restrict__ sW2,
                             const float* __restrict__ sW3,
                             const float* __restrict__ jW1,
                             const float* __restrict__ jW2,
                             const float* __restrict__ jW3,
                             f16* __restrict__ wbuf)
{
    int idx = blockIdx.x * 256 + threadIdx.x;
    if (idx >= W_TOTAL) return;
    const float* W;
    int off, M, K;
    if (idx < OFF_S2)      { off = OFF_S1; M = 128; K = 32;  W = sW1; }
    else if (idx < OFF_S3) { off = OFF_S2; M = 128; K = 128; W = sW2; }
    else if (idx < OFF_J1) { off = OFF_S3; M = 32;  K = 128; W = sW3; }
    else if (idx < OFF_J2) { off = OFF_J1; M = 128; K = 96;  W = jW1; }
    else if (idx < OFF_J3) { off = OFF_J2; M = 128; K = 128; W = jW2; }
    else                   { off = OFF_J3; M = 32;  K = 128; W = jW3; }
    int r = idx - off;
    int m = r / K;
    int k = r - m * K;
    wbuf[idx] = (f16)W[(size_t)k * M + m];   // W^T[m][k] = W[k][m]
}

__device__ __forceinline__ void gload16(const void* g, void* l)
{
    // async global->LDS, 16 B/lane; LDS dest = wave-uniform base + lane*16
    __builtin_amdgcn_global_load_lds(
        (const __attribute__((address_space(1))) void*)g,
        (__attribute__((address_space(3))) void*)l,
        16, 0, 0);
}

// Fused 3-layer MLP level. Block = 256 threads = 4 waves; 32 rows (2 groups
// of 16) per iteration. Wave w owns M-rows [32w,32w+32) of layers 1/2;
// layer 3 (M=32): wave w handles group (w&1), M-half (w>>1).
template <bool LEAF>
__global__ __launch_bounds__(256, 3)
void mlp_level(const float* __restrict__ feats,
               const f16*   __restrict__ cur_in,
               f16*         __restrict__ cur_out,
               float*       __restrict__ out_final,
               const f16*   __restrict__ W1t,
               const f16*   __restrict__ W2t,
               const f16*   __restrict__ W3t,
               const float* __restrict__ b1,
               const float* __restrict__ b2,
               const float* __restrict__ b3,
               int rows, int log2n, int foff, int is_last)
{
    constexpr int K1    = LEAF ? 32 : 96;
    constexpr int NK1   = LEAF ? 1 : 3;   // feats (+ curL + curR) K-steps
    constexpr int PITCH = 136;            // f16/row = 272 B

    __shared__ __align__(16) f16   h1[32 * PITCH];
    __shared__ __align__(16) f16   h2[32 * PITCH];
    __shared__ __align__(16) float fstage[2][32 * 32];          // 2 x 4 KB
    __shared__ __align__(16) f16   cstage[(LEAF ? 1 : 2)][32 * 64]; // join: 2 x 4 KB

    const int tid  = threadIdx.x;
    const int wave = tid >> 6;
    const int lane = tid & 63;
    const int n    = lane & 15;   // node-local index (N dim of MFMA)
    const int q    = lane >> 4;
    const int n7   = n & 7;
    const int mrow = 32 * wave;   // L1/L2 M-slice base
    const int l3g  = wave & 1;    // L3: which group
    const int l3h  = wave >> 1;   // L3: which 16-row M-half

    // staging lane constants: wave w stages quarter w of the 32-row tile.
    // dest chunk (linear) = w*64 + lane; row = w*8 + lane/8; stored chunk
    // index c' = lane&7 corresponds to source chunk c = c' ^ (row&7).
    const int srow   = (wave << 3) + (lane >> 3);
    const int schunk = (lane & 7) ^ (lane >> 3);

    // ---- resident weights (A[m][k]; m = mrow + 16*mt + n, k = 32*ks+8*q+j)
    f16x8 A1[2][NK1], A2[2][4], A3[4];
#pragma unroll
    for (int mt = 0; mt < 2; ++mt)
#pragma unroll
        for (int ks = 0; ks < NK1; ++ks)
            A1[mt][ks] = *(const f16x8*)(W1t + (size_t)(mrow + 16 * mt + n) * K1 + 32 * ks + 8 * q);
#pragma unroll
    for (int mt = 0; mt < 2; ++mt)
#pragma unroll
        for (int ks = 0; ks < 4; ++ks)
            A2[mt][ks] = *(const f16x8*)(W2t + (size_t)(mrow + 16 * mt + n) * 128 + 32 * ks + 8 * q);
#pragma unroll
    for (int ks = 0; ks < 4; ++ks)
        A3[ks] = *(const f16x8*)(W3t + (size_t)(16 * l3h + n) * 128 + 32 * ks + 8 * q);

    // ---- bias fragments: C[mt][reg] row m = mrow + 16*mt + 4*q + reg
    f32x4 bf1[2], bf2[2], bf3;
#pragma unroll
    for (int mt = 0; mt < 2; ++mt) {
        bf1[mt] = *(const f32x4*)(b1 + mrow + 16 * mt + 4 * q);
        bf2[mt] = *(const f32x4*)(b2 + mrow + 16 * mt + 4 * q);
    }
    bf3 = *(const f32x4*)(b3 + 16 * l3h + 4 * q);

    // ---- async stage of one 32-row tile into LDS buffer sb.
    // feats: rows of 32 f32 = 128 B = 8 chunks; cur: parent row gr's
    // children (2gr,2gr+1) = 128 B contiguous = 8 chunks. Source chunk
    // pre-swizzled so LDS holds chunk c of row r at position c^(r&7).
    auto stage = [&](int tg0, int sb) {
        int gr = tg0 + srow;
        const float* fsrc;
        if constexpr (LEAF) {
            fsrc = feats + (size_t)gr * 32 + schunk * 4;
        } else {
            int bb = gr >> log2n;
            int ii = gr & ((1 << log2n) - 1);
            fsrc = feats + ((size_t)bb * 1023 + foff + ii) * 32 + schunk * 4;
        }
        gload16(fsrc, &fstage[sb][wave * 256]);
        if constexpr (!LEAF)
            gload16(cur_in + (size_t)gr * 64 + schunk * 8, &cstage[sb][wave * 512]);
    };

    const int stride = gridDim.x * 32;
    int g0 = blockIdx.x * 32;
    if (g0 >= rows) return;          // uniform per block; grid never exceeds

    int rb = 0;
    stage(g0, 0);                    // prologue: tile 0 in flight

    for (; g0 < rows; g0 += stride) {
        // issue next tile's stage first — stays in flight across barrier
        int gnext = g0 + stride;
        stage(gnext < rows ? gnext : g0, rb ^ 1);

        // wait for THIS tile's stage (issued last iter). Queue per wave:
        // [stage_i(K), (store_{i-1}: 0|1), stage_{i+1}(K)]; vmcnt(K) drains
        // stage_i (+ the store if present) for every wave shape. Never 0.
        if constexpr (LEAF) asm volatile("s_waitcnt vmcnt(1)" ::: "memory");
        else                asm volatile("s_waitcnt vmcnt(2)" ::: "memory");
        __builtin_amdgcn_s_barrier();      // all waves' quarters landed

        // ---------------- layer 1 ----------------
        f32x4 C[2][2];
#pragma unroll
        for (int g = 0; g < 2; ++g)
#pragma unroll
            for (int mt = 0; mt < 2; ++mt) C[g][mt] = bf1[mt];

#pragma unroll
        for (int g = 0; g < 2; ++g) {
            const int r = 16 * g + n;
            // feats cols 8q..8q+7 (f32): chunks 2q, 2q+1, swizzled by r&7=n7
            f32x4 fa = *(const f32x4*)(&fstage[rb][r * 32 + (((2 * q)     ^ n7) * 4)]);
            f32x4 fb = *(const f32x4*)(&fstage[rb][r * 32 + (((2 * q + 1) ^ n7) * 4)]);
            f16x8 Bf;
#pragma unroll
            for (int j = 0; j < 4; ++j) {
                Bf[j]     = (f16)fa[j];
                Bf[4 + j] = (f16)fb[j];
            }
#pragma unroll
            for (int mt = 0; mt < 2; ++mt) C[g][mt] = MFMA16(A1[mt][0], Bf, C[g][mt]);
            if constexpr (!LEAF) {
                // left child = chunks 0..3 (chunk q), right = 4..7 (chunk 4+q)
                f16x8 cl = *(const f16x8*)(&cstage[rb][r * 64 + ((q       ^ n7) * 8)]);
                f16x8 cr = *(const f16x8*)(&cstage[rb][r * 64 + (((4 + q) ^ n7) * 8)]);
#pragma unroll
                for (int mt = 0; mt < 2; ++mt) C[g][mt] = MFMA16(A1[mt][1], cl, C[g][mt]);
#pragma unroll
                for (int mt = 0; mt < 2; ++mt) C[g][mt] = MFMA16(A1[mt][2], cr, C[g][mt]);
            }
        }
        // relu + pack -> h1[16g+n][mrow + 16mt + 4q + reg]
#pragma unroll
        for (int g = 0; g < 2; ++g)
#pragma unroll
            for (int mt = 0; mt < 2; ++mt) {
                f16x4 pk;
                pk[0] = (f16)fmaxf(C[g][mt][0], 0.0f);
                pk[1] = (f16)fmaxf(C[g][mt][1], 0.0f);
                pk[2] = (f16)fmaxf(C[g][mt][2], 0.0f);
                pk[3] = (f16)fmaxf(C[g][mt][3], 0.0f);
                *(f16x4*)(h1 + (16 * g + n) * PITCH + mrow + 16 * mt + 4 * q) = pk;
            }
        asm volatile("s_waitcnt lgkmcnt(0)" ::: "memory");   // h1 writes drained
        __builtin_amdgcn_s_barrier();

        // ---------------- layer 2 ----------------
#pragma unroll
        for (int g = 0; g < 2; ++g)
#pragma unroll
            for (int mt = 0; mt < 2; ++mt) C[g][mt] = bf2[mt];
#pragma unroll
        for (int ks = 0; ks < 4; ++ks)
#pragma unroll
            for (int g = 0; g < 2; ++g) {
                f16x8 Bf = *(const f16x8*)(h1 + (16 * g + n) * PITCH + 32 * ks + 8 * q);
#pragma unroll
                for (int mt = 0; mt < 2; ++mt) C[g][mt] = MFMA16(A2[mt][ks], Bf, C[g][mt]);
            }
#pragma unroll
        for (int g = 0; g < 2; ++g)
#pragma unroll
            for (int mt = 0; mt < 2; ++mt) {
                f16x4 pk;
                pk[0] = (f16)fmaxf(C[g][mt][0], 0.0f);
                pk[1] = (f16)fmaxf(C[g][mt][1], 0.0f);
                pk[2] = (f16)fmaxf(C[g][mt][2], 0.0f);
                pk[3] = (f16)fmaxf(C[g][mt][3], 0.0f);
                *(f16x4*)(h2 + (16 * g + n) * PITCH + mrow + 16 * mt + 4 * q) = pk;
            }
        asm volatile("s_waitcnt lgkmcnt(0)" ::: "memory");   // h2 writes drained
        __builtin_amdgcn_s_barrier();

        // ---------------- layer 3 (wave -> group l3g, M-half l3h) --------
        f32x4 C3 = bf3;
#pragma unroll
        for (int ks = 0; ks < 4; ++ks) {
            f16x8 Bf = *(const f16x8*)(h2 + (16 * l3g + n) * PITCH + 32 * ks + 8 * q);
            C3 = MFMA16(A3[ks], Bf, C3);
        }

        if (is_last) {
            // out[b] = cur[:,0,0]: o=0 -> l3h==0, q==0, reg 0
            if (l3h == 0 && q == 0) out_final[g0 + 16 * l3g + n] = C3[0];
        } else {
            f16x4 pk;
            pk[0] = (f16)C3[0]; pk[1] = (f16)C3[1]; pk[2] = (f16)C3[2]; pk[3] = (f16)C3[3];
            *(f16x4*)(cur_out + (size_t)(g0 + 16 * l3g + n) * 32 + 16 * l3h + 4 * q) = pk;
        }
        // race-safety: next iter's h1 write sits behind next iter's
        // post-stage barrier; this iter's h1/h2 reads drain before their
        // consuming MFMAs, hence before this iter's trailing barriers.

        rb ^= 1;
    }
}

extern "C" void kernel_launch(void* const* d_in, const int* in_sizes, int n_in,
                              void* d_out, int out_size, void* d_ws, size_t ws_size,
                              hipStream_t stream)
{
    const float* leaf_feats     = (const float*)d_in[0];
    const float* internal_feats = (const float*)d_in[1];
    const float* sW1 = (const float*)d_in[2];  const float* sb1 = (const float*)d_in[3];
    const float* sW2 = (const float*)d_in[4];  const float* sb2 = (const float*)d_in[5];
    const float* sW3 = (const float*)d_in[6];  const float* sb3 = (const float*)d_in[7];
    const float* jW1 = (const float*)d_in[8];  const float* jb1 = (const float*)d_in[9];
    const float* jW2 = (const float*)d_in[10]; const float* jb2 = (const float*)d_in[11];
    const float* jW3 = (const float*)d_in[12]; const float* jb3 = (const float*)d_in[13];

    f16* wbuf = (f16*)d_ws;
    f16* curA = (f16*)((char*)d_ws + CURA_BYTE_OFF);                 // 128 MB
    f16* curB = (f16*)((char*)d_ws + CURA_BYTE_OFF + 134217728);     // 64 MB

    prep_weights<<<(W_TOTAL + 255) / 256, 256, 0, stream>>>(
        sW1, sW2, sW3, jW1, jW2, jW3, wbuf);

    // leaf level: 2048*1024 rows, 65536 iterations of 32 rows
    mlp_level<true><<<2048, 256, 0, stream>>>(
        leaf_feats, nullptr, curA, nullptr,
        wbuf + OFF_S1, wbuf + OFF_S2, wbuf + OFF_S3,
        sb1, sb2, sb3,
        2048 * 1024, 0, 0, 0);

    // join levels
    const f16* cin = curA;
    f16* cout = curB;
    int off = 0, lg = 9;
    for (int nlev = 512; nlev >= 1; nlev >>= 1, --lg) {
        int rows  = 2048 * nlev;
        int iters = rows / 32;
        int grid  = iters < 2048 ? iters : 2048;
        mlp_level<false><<<grid, 256, 0, stream>>>(
            internal_feats, cin, cout, (float*)d_out,
            wbuf + OFF_J1, wbuf + OFF_J2, wbuf + OFF_J3,
            jb1, jb2, jb3,
            rows, lg, off, (nlev == 1) ? 1 : 0);
        off += nlev;
        f16* t = cout; cout = (f16*)cin; cin = t;
    }
}